// Round 1
// baseline (250.224 us; speedup 1.0000x reference)
//
#include <hip/hip_runtime.h>
#include <math.h>

#define NLAYER_TOT 12
#define LAYER0 4
#define SMAX 512
#define DIM 768
// B=8 sentences, 8 used layers, T = mask.sum(row0)-1 (511 for the given inputs)

// ---------------- kernel 0: compute T, zero output ----------------
__global__ void k_init(const int* __restrict__ mask, int* __restrict__ wsT,
                       float* __restrict__ out) {
    __shared__ int red[512];
    int tid = threadIdx.x;
    red[tid] = mask[tid];  // row 0 of attention_mask
    __syncthreads();
    for (int s = 256; s >= 1; s >>= 1) {
        if (tid < s) red[tid] += red[tid + s];
        __syncthreads();
    }
    if (tid == 0) wsT[0] = red[0] - 1;
    for (int i = tid; i < 8 * DIM; i += 512) out[i] = 0.0f;
}

// ---------------- kernel 1: per-(b,t) 8x8 Gram (packed upper-tri, 36 floats) ----------------
__global__ __launch_bounds__(64) void k_gram(const float* __restrict__ in,
                                             const int* __restrict__ wsT,
                                             float* __restrict__ Gout) {
    int T = wsT[0];
    int t = blockIdx.x;
    int b = blockIdx.y;
    if (t >= T) return;
    int lane = threadIdx.x;
    const float* base = in + ((size_t)(b * NLAYER_TOT + LAYER0) * SMAX + t) * DIM;
    float acc[36];
#pragma unroll
    for (int p = 0; p < 36; ++p) acc[p] = 0.0f;
#pragma unroll
    for (int it = 0; it < 3; ++it) {
        int d = it * 256 + lane * 4;  // 64 lanes * 4 floats = 256 per iter, 3 iters = 768
        float4 x[8];
#pragma unroll
        for (int k = 0; k < 8; ++k)
            x[k] = *(const float4*)(base + (size_t)k * SMAX * DIM + d);
        int p = 0;
#pragma unroll
        for (int i = 0; i < 8; ++i)
#pragma unroll
            for (int j = i; j < 8; ++j) {
                acc[p] += x[i].x * x[j].x + x[i].y * x[j].y + x[i].z * x[j].z + x[i].w * x[j].w;
                ++p;
            }
    }
    float* gdst = Gout + ((size_t)b * SMAX + t) * 36;
#pragma unroll
    for (int p = 0; p < 36; ++p) {
        float v = acc[p];
#pragma unroll
        for (int off = 32; off >= 1; off >>= 1) v += __shfl_xor(v, off, 64);
        if (lane == 0) gdst[p] = v;
    }
}

// ---------------- per-k small math: Cholesky of Gram subset -> align, nov ----------------
// QR's R equals chol(G) up to per-row sign flips; align & nov are invariant to those flips.
template <int W>
__device__ inline void alpha_nov(const float* __restrict__ Gf, const int* __restrict__ idx,
                                 double& align_o, double& nov_o) {
    double Gs[W][W];
#pragma unroll
    for (int i = 0; i < W; ++i)
#pragma unroll
        for (int j = 0; j < W; ++j) Gs[i][j] = (double)Gf[idx[i] * 8 + idx[j]];
    double R[W][W];
#pragma unroll
    for (int j = 0; j < W; ++j)
#pragma unroll
        for (int i = 0; i <= j; ++i) {
            double s = Gs[i][j];
#pragma unroll
            for (int q = 0; q < i; ++q) s -= R[q][i] * R[q][j];
            R[i][j] = (i == j) ? sqrt(s) : (s / R[i][i]);
        }
    // coln[j] (column norms of sub) == sqrt(Gs[j][j]) for j < W-1
    double m[W - 1];
#pragma unroll
    for (int i = 0; i < W - 1; ++i) {
        double s = 0.0;
#pragma unroll
        for (int j = i; j < W - 1; ++j) s += R[i][j] / sqrt(Gs[j][j]);
        m[i] = s / (double)(W - 1);
    }
    double num = 0.0, n1 = 0.0;
#pragma unroll
    for (int i = 0; i < W - 1; ++i) {
        num += m[i] * R[i][W - 1];
        n1 += R[i][W - 1] * R[i][W - 1];
    }
    double align_raw = num / sqrt(n1);
    align_o = 1.0 / (align_raw * (double)W * 2.0);
    nov_o = fabs(R[W - 1][W - 1]) / sqrt(Gs[W - 1][W - 1]);  // |r[-1]| / ||r||
}

// ---------------- kernel 2: per-token alpha (normalized) + raw variance ----------------
__global__ void k_alpha(const int* __restrict__ wsT, const float* __restrict__ Gin,
                        float* __restrict__ alpha, float* __restrict__ vraw) {
    int T = wsT[0];
    int id = blockIdx.x * blockDim.x + threadIdx.x;
    int b = id >> 9;
    int t = id & 511;
    if (b >= 8 || t >= T) return;
    float Gf[64];
    const float* gsrc = Gin + ((size_t)b * SMAX + t) * 36;
    {
        int p = 0;
#pragma unroll
        for (int i = 0; i < 8; ++i)
#pragma unroll
            for (int j = i; j < 8; ++j) {
                float v = gsrc[p++];
                Gf[i * 8 + j] = v;
                Gf[j * 8 + i] = v;
            }
    }
    // Reference: left window only when k >= WS(=2); right = k+1..min(k+2,7); then k last.
    static constexpr int IDX0[5] = {1, 2, 0, 0, 0};
    static constexpr int IDX1[5] = {2, 3, 1, 0, 0};
    static constexpr int IDX2[5] = {0, 1, 3, 4, 2};
    static constexpr int IDX3[5] = {1, 2, 4, 5, 3};
    static constexpr int IDX4[5] = {2, 3, 5, 6, 4};
    static constexpr int IDX5[5] = {3, 4, 6, 7, 5};
    static constexpr int IDX6[5] = {4, 5, 7, 6, 0};
    static constexpr int IDX7[5] = {5, 6, 7, 0, 0};
    double a[8], n[8];
    alpha_nov<3>(Gf, IDX0, a[0], n[0]);
    alpha_nov<3>(Gf, IDX1, a[1], n[1]);
    alpha_nov<5>(Gf, IDX2, a[2], n[2]);
    alpha_nov<5>(Gf, IDX3, a[3], n[3]);
    alpha_nov<5>(Gf, IDX4, a[4], n[4]);
    alpha_nov<5>(Gf, IDX5, a[5], n[5]);
    alpha_nov<4>(Gf, IDX6, a[6], n[6]);
    alpha_nov<3>(Gf, IDX7, a[7], n[7]);
    double sa = 0.0, sn = 0.0;
#pragma unroll
    for (int k = 0; k < 8; ++k) { sa += a[k]; sn += n[k]; }
    double al[8], ss = 0.0;
#pragma unroll
    for (int k = 0; k < 8; ++k) { al[k] = a[k] / sa + n[k] / sn; ss += al[k]; }
    float* adst = alpha + ((size_t)b * SMAX + t) * 8;
#pragma unroll
    for (int k = 0; k < 8; ++k) adst[k] = (float)(al[k] / ss);
    // token variance: subdiagonal cosine similarities of consecutive layers
    double c[7], mu = 0.0;
#pragma unroll
    for (int i = 0; i < 7; ++i) {
        double denom = sqrt((double)Gf[i * 8 + i]) * sqrt((double)Gf[(i + 1) * 8 + (i + 1)]);
        denom = denom > 1e-8 ? denom : 1e-8;
        c[i] = (double)Gf[(i + 1) * 8 + i] / denom;
        mu += c[i];
    }
    mu /= 7.0;
    double var = 0.0;
#pragma unroll
    for (int i = 0; i < 7; ++i) var += (c[i] - mu) * (c[i] - mu);
    vraw[(size_t)b * SMAX + t] = (float)(var / 6.0);  // ddof=1
}

// ---------------- kernel 3: per-sentence v normalization, fold into W[b,t,k] ----------------
__global__ void k_weights(const int* __restrict__ wsT, const float* __restrict__ alpha,
                          const float* __restrict__ vraw, float* __restrict__ W) {
    int T = wsT[0];
    int b = blockIdx.x;
    int tid = threadIdx.x;
    __shared__ float red[256];
    float s = 0.0f;
    for (int t = tid; t < T; t += 256) s += vraw[(size_t)b * SMAX + t];
    red[tid] = s;
    __syncthreads();
    for (int k = 128; k >= 1; k >>= 1) {
        if (tid < k) red[tid] += red[tid + k];
        __syncthreads();
    }
    float inv = 1.0f / red[0];
    for (int t = tid; t < T; t += 256) {
        float v = vraw[(size_t)b * SMAX + t] * inv;
#pragma unroll
        for (int k = 0; k < 8; ++k)
            W[((size_t)b * SMAX + t) * 8 + k] = alpha[((size_t)b * SMAX + t) * 8 + k] * v;
    }
}

// ---------------- kernel 4: out[b,d] = sum_{t,k} W[b,t,k] * sf[b,k,t,d] ----------------
__global__ void k_out(const float* __restrict__ in, const int* __restrict__ wsT,
                      const float* __restrict__ W, float* __restrict__ out) {
    int T = wsT[0];
    int tseg = blockIdx.x;   // 0..31, 16 tokens each
    int dchunk = blockIdx.y; // 0..2
    int b = blockIdx.z;      // 0..7
    int d = dchunk * 256 + threadIdx.x;
    int t0 = tseg * 16;
    int t1 = min(t0 + 16, T);
    if (t0 >= t1) return;
    const float* base = in + ((size_t)(b * NLAYER_TOT + LAYER0) * SMAX) * DIM + d;
    const float* wb = W + (size_t)b * SMAX * 8;
    float acc = 0.0f;
    for (int t = t0; t < t1; ++t) {
#pragma unroll
        for (int k = 0; k < 8; ++k)
            acc += wb[t * 8 + k] * base[((size_t)k * SMAX + t) * DIM];
    }
    atomicAdd(&out[b * DIM + d], acc);
}

extern "C" void kernel_launch(void* const* d_in, const int* in_sizes, int n_in,
                              void* d_out, int out_size, void* d_ws, size_t ws_size,
                              hipStream_t stream) {
    const float* hs = (const float*)d_in[0];   // (8, 12, 512, 768) f32
    const int* mask = (const int*)d_in[1];     // (8, 512) i32
    float* out = (float*)d_out;                // (8, 768) f32
    char* ws = (char*)d_ws;
    // ws layout (bytes): [0] int T | [256] G 8*512*36 f | alpha 8*512*8 f | vraw 8*512 f | W 8*512*8 f
    int* wsT = (int*)ws;
    float* G = (float*)(ws + 256);
    float* alpha = (float*)(ws + 256 + (size_t)8 * 512 * 36 * 4);
    float* vraw = (float*)(ws + 256 + (size_t)(8 * 512 * 36 + 8 * 512 * 8) * 4);
    float* W = (float*)(ws + 256 + (size_t)(8 * 512 * 36 + 8 * 512 * 8 + 8 * 512) * 4);

    k_init<<<1, 512, 0, stream>>>(mask, wsT, out);
    k_gram<<<dim3(SMAX - 1, 8), 64, 0, stream>>>(hs, wsT, G);
    k_alpha<<<16, 256, 0, stream>>>(wsT, G, alpha, vraw);
    k_weights<<<8, 256, 0, stream>>>(wsT, alpha, vraw, W);
    k_out<<<dim3(32, 3, 8), 256, 0, stream>>>(hs, wsT, W, out);
}

// Round 2
// 249.573 us; speedup vs baseline: 1.0026x; 1.0026x over previous
//
#include <hip/hip_runtime.h>
#include <math.h>

#define NLAYER_TOT 12
#define LAYER0 4
#define SMAX 512
#define DIM 768
// B=8 sentences, 8 used layers, T = mask.sum(row0)-1 (511 for the given inputs)

// ---------------- kernel 0: compute T, zero output ----------------
__global__ void k_init(const int* __restrict__ mask, int* __restrict__ wsT,
                       float* __restrict__ out) {
    __shared__ int red[512];
    int tid = threadIdx.x;
    red[tid] = mask[tid];  // row 0 of attention_mask
    __syncthreads();
    for (int s = 256; s >= 1; s >>= 1) {
        if (tid < s) red[tid] += red[tid + s];
        __syncthreads();
    }
    if (tid == 0) wsT[0] = red[0] - 1;
    for (int i = tid; i < 8 * DIM; i += 512) out[i] = 0.0f;
}

// ---------------- kernel 1: per-(b,t) 8x8 Gram (packed upper-tri, 36 floats) ----------------
__global__ __launch_bounds__(64) void k_gram(const float* __restrict__ in,
                                             const int* __restrict__ wsT,
                                             float* __restrict__ Gout) {
    int T = wsT[0];
    int t = blockIdx.x;
    int b = blockIdx.y;
    if (t >= T) return;
    int lane = threadIdx.x;
    const float* base = in + ((size_t)(b * NLAYER_TOT + LAYER0) * SMAX + t) * DIM;
    float acc[36];
#pragma unroll
    for (int p = 0; p < 36; ++p) acc[p] = 0.0f;
#pragma unroll
    for (int it = 0; it < 3; ++it) {
        int d = it * 256 + lane * 4;  // 64 lanes * 4 floats = 256 per iter, 3 iters = 768
        float4 x[8];
#pragma unroll
        for (int k = 0; k < 8; ++k)
            x[k] = *(const float4*)(base + (size_t)k * SMAX * DIM + d);
        int p = 0;
#pragma unroll
        for (int i = 0; i < 8; ++i)
#pragma unroll
            for (int j = i; j < 8; ++j) {
                acc[p] += x[i].x * x[j].x + x[i].y * x[j].y + x[i].z * x[j].z + x[i].w * x[j].w;
                ++p;
            }
    }
    float* gdst = Gout + ((size_t)b * SMAX + t) * 36;
#pragma unroll
    for (int p = 0; p < 36; ++p) {
        float v = acc[p];
#pragma unroll
        for (int off = 32; off >= 1; off >>= 1) v += __shfl_xor(v, off, 64);
        if (lane == 0) gdst[p] = v;
    }
}

// ---------------- per-k small math: Cholesky of Gram subset -> align, nov ----------------
// QR's R equals chol(G) up to per-row sign flips; align & nov are invariant to those flips.
// All-float: G is well conditioned (diag ~768, offdiag ~±28); f32 error << 7e-2 threshold.
template <int W>
__device__ inline void alpha_nov(const float* __restrict__ Gf, const int* __restrict__ idx,
                                 float& align_o, float& nov_o) {
    float Gs[W][W];
#pragma unroll
    for (int i = 0; i < W; ++i)
#pragma unroll
        for (int j = i; j < W; ++j) {
            float v = Gf[idx[i] * 8 + idx[j]];
            Gs[i][j] = v;
            Gs[j][i] = v;
        }
    float R[W][W];
#pragma unroll
    for (int j = 0; j < W; ++j) {
#pragma unroll
        for (int i = 0; i <= j; ++i) {
            float s = Gs[i][j];
#pragma unroll
            for (int q = 0; q < i; ++q) s -= R[q][i] * R[q][j];
            R[i][j] = (i == j) ? sqrtf(s) : (s / R[i][i]);
        }
    }
    // coln[j] (column norms of sub) == sqrt(Gs[j][j]) for j < W-1
    float ic[W - 1];
#pragma unroll
    for (int j = 0; j < W - 1; ++j) ic[j] = 1.0f / sqrtf(Gs[j][j]);
    float m[W - 1];
#pragma unroll
    for (int i = 0; i < W - 1; ++i) {
        float s = 0.0f;
#pragma unroll
        for (int j = i; j < W - 1; ++j) s += R[i][j] * ic[j];
        m[i] = s * (1.0f / (float)(W - 1));
    }
    float num = 0.0f, n1 = 0.0f;
#pragma unroll
    for (int i = 0; i < W - 1; ++i) {
        num += m[i] * R[i][W - 1];
        n1 += R[i][W - 1] * R[i][W - 1];
    }
    float align_raw = num / sqrtf(n1);
    align_o = 1.0f / (align_raw * (float)W * 2.0f);
    nov_o = fabsf(R[W - 1][W - 1]) / sqrtf(Gs[W - 1][W - 1]);  // |r[-1]| / ||r||
}

// ---------------- kernel 2: per-token alpha (normalized) + raw variance ----------------
__global__ __launch_bounds__(64) void k_alpha(const int* __restrict__ wsT,
                                              const float* __restrict__ Gin,
                                              float* __restrict__ alpha,
                                              float* __restrict__ vraw) {
    int T = wsT[0];
    int id = blockIdx.x * 64 + threadIdx.x;
    int b = id >> 9;
    int t = id & 511;
    if (b >= 8 || t >= T) return;
    float Gf[64];
    const float* gsrc = Gin + ((size_t)b * SMAX + t) * 36;
    {
        int p = 0;
#pragma unroll
        for (int i = 0; i < 8; ++i)
#pragma unroll
            for (int j = i; j < 8; ++j) {
                float v = gsrc[p++];
                Gf[i * 8 + j] = v;
                Gf[j * 8 + i] = v;
            }
    }
    // Reference: left window only when k >= WS(=2); right = k+1..min(k+2,7); then k last.
    static constexpr int IDX0[5] = {1, 2, 0, 0, 0};
    static constexpr int IDX1[5] = {2, 3, 1, 0, 0};
    static constexpr int IDX2[5] = {0, 1, 3, 4, 2};
    static constexpr int IDX3[5] = {1, 2, 4, 5, 3};
    static constexpr int IDX4[5] = {2, 3, 5, 6, 4};
    static constexpr int IDX5[5] = {3, 4, 6, 7, 5};
    static constexpr int IDX6[5] = {4, 5, 7, 6, 0};
    static constexpr int IDX7[5] = {5, 6, 7, 0, 0};
    float a[8], n[8];
    alpha_nov<3>(Gf, IDX0, a[0], n[0]);
    alpha_nov<3>(Gf, IDX1, a[1], n[1]);
    alpha_nov<5>(Gf, IDX2, a[2], n[2]);
    alpha_nov<5>(Gf, IDX3, a[3], n[3]);
    alpha_nov<5>(Gf, IDX4, a[4], n[4]);
    alpha_nov<5>(Gf, IDX5, a[5], n[5]);
    alpha_nov<4>(Gf, IDX6, a[6], n[6]);
    alpha_nov<3>(Gf, IDX7, a[7], n[7]);
    float sa = 0.0f, sn = 0.0f;
#pragma unroll
    for (int k = 0; k < 8; ++k) { sa += a[k]; sn += n[k]; }
    float isa = 1.0f / sa, isn = 1.0f / sn;
    float al[8], ss = 0.0f;
#pragma unroll
    for (int k = 0; k < 8; ++k) { al[k] = a[k] * isa + n[k] * isn; ss += al[k]; }
    float iss = 1.0f / ss;
    float* adst = alpha + ((size_t)b * SMAX + t) * 8;
#pragma unroll
    for (int k = 0; k < 8; ++k) adst[k] = al[k] * iss;
    // token variance: subdiagonal cosine similarities of consecutive layers
    float c[7], mu = 0.0f;
#pragma unroll
    for (int i = 0; i < 7; ++i) {
        float denom = sqrtf(Gf[i * 8 + i]) * sqrtf(Gf[(i + 1) * 8 + (i + 1)]);
        denom = denom > 1e-8f ? denom : 1e-8f;
        c[i] = Gf[(i + 1) * 8 + i] / denom;
        mu += c[i];
    }
    mu *= (1.0f / 7.0f);
    float var = 0.0f;
#pragma unroll
    for (int i = 0; i < 7; ++i) var += (c[i] - mu) * (c[i] - mu);
    vraw[(size_t)b * SMAX + t] = var * (1.0f / 6.0f);  // ddof=1
}

// ---------------- kernel 3: per-sentence v normalization, fold into W[b,t,k] ----------------
__global__ void k_weights(const int* __restrict__ wsT, const float* __restrict__ alpha,
                          const float* __restrict__ vraw, float* __restrict__ W) {
    int T = wsT[0];
    int b = blockIdx.x;
    int tid = threadIdx.x;
    __shared__ float red[256];
    float s = 0.0f;
    for (int t = tid; t < T; t += 256) s += vraw[(size_t)b * SMAX + t];
    red[tid] = s;
    __syncthreads();
    for (int k = 128; k >= 1; k >>= 1) {
        if (tid < k) red[tid] += red[tid + k];
        __syncthreads();
    }
    float inv = 1.0f / red[0];
    for (int t = tid; t < T; t += 256) {
        float v = vraw[(size_t)b * SMAX + t] * inv;
#pragma unroll
        for (int k = 0; k < 8; ++k)
            W[((size_t)b * SMAX + t) * 8 + k] = alpha[((size_t)b * SMAX + t) * 8 + k] * v;
    }
}

// ---------------- kernel 4: out[b,d] = sum_{t,k} W[b,t,k] * sf[b,k,t,d] ----------------
__global__ void k_out(const float* __restrict__ in, const int* __restrict__ wsT,
                      const float* __restrict__ W, float* __restrict__ out) {
    int T = wsT[0];
    int tseg = blockIdx.x;   // 0..31, 16 tokens each
    int dchunk = blockIdx.y; // 0..2
    int b = blockIdx.z;      // 0..7
    int d = dchunk * 256 + threadIdx.x;
    int t0 = tseg * 16;
    int t1 = min(t0 + 16, T);
    if (t0 >= t1) return;
    const float* base = in + ((size_t)(b * NLAYER_TOT + LAYER0) * SMAX) * DIM + d;
    const float* wb = W + (size_t)b * SMAX * 8;
    float acc = 0.0f;
    for (int t = t0; t < t1; ++t) {
#pragma unroll
        for (int k = 0; k < 8; ++k)
            acc += wb[t * 8 + k] * base[((size_t)k * SMAX + t) * DIM];
    }
    atomicAdd(&out[b * DIM + d], acc);
}

extern "C" void kernel_launch(void* const* d_in, const int* in_sizes, int n_in,
                              void* d_out, int out_size, void* d_ws, size_t ws_size,
                              hipStream_t stream) {
    const float* hs = (const float*)d_in[0];   // (8, 12, 512, 768) f32
    const int* mask = (const int*)d_in[1];     // (8, 512) i32
    float* out = (float*)d_out;                // (8, 768) f32
    char* ws = (char*)d_ws;
    // ws layout (bytes): [0] int T | [256] G 8*512*36 f | alpha 8*512*8 f | vraw 8*512 f | W 8*512*8 f
    int* wsT = (int*)ws;
    float* G = (float*)(ws + 256);
    float* alpha = (float*)(ws + 256 + (size_t)8 * 512 * 36 * 4);
    float* vraw = (float*)(ws + 256 + (size_t)(8 * 512 * 36 + 8 * 512 * 8) * 4);
    float* W = (float*)(ws + 256 + (size_t)(8 * 512 * 36 + 8 * 512 * 8 + 8 * 512) * 4);

    k_init<<<1, 512, 0, stream>>>(mask, wsT, out);
    k_gram<<<dim3(SMAX - 1, 8), 64, 0, stream>>>(hs, wsT, G);
    k_alpha<<<64, 64, 0, stream>>>(wsT, G, alpha, vraw);
    k_weights<<<8, 256, 0, stream>>>(wsT, alpha, vraw, W);
    k_out<<<dim3(32, 3, 8), 256, 0, stream>>>(hs, wsT, W, out);
}